// Round 4
// baseline (89.910 us; speedup 1.0000x reference)
//
#include <hip/hip_runtime.h>
#include <math.h>

#define BS    8192
#define NCTX  28
#define DM    28
#define IPB   4
#define BLOCK (IPB*32)      // 128 threads, 2 waves
#define QSTRIDE 28          // q row stride in LDS: 112B, 16B-aligned
#define WTS   96            // transposed weight row stride (floats)

// g_wt[w*WTS + c]: c 0..27 = Wq col w, 28..55 = Wk, 56..83 = Wv
__device__ float g_wt[NCTX * WTS];

__global__ void transpose_weights(const float* __restrict__ Wq,
                                  const float* __restrict__ Wk,
                                  const float* __restrict__ Wv)
{
    int t = threadIdx.x;
    for (int i = t; i < DM * DM; i += blockDim.x) {
        int c = i / DM, w = i % DM;
        g_wt[w*WTS + c]      = Wq[c*DM + w];
        g_wt[w*WTS + 28 + c] = Wk[c*DM + w];
        g_wt[w*WTS + 56 + c] = Wv[c*DM + w];
    }
}

__global__ __launch_bounds__(BLOCK, 8) void l1att_fused(
    const float* __restrict__ x,
    const float* __restrict__ bq, const float* __restrict__ bk,
    const float* __restrict__ bv,
    const float* __restrict__ W1, const float* __restrict__ b1,
    const float* __restrict__ W2, const float* __restrict__ b2,
    float* __restrict__ out)
{
    __shared__ float qs[IPB][NCTX*QSTRIDE];   // 12544 B
    __shared__ float l1_lds[IPB][NCTX];
    __shared__ float h_lds[IPB][20];

    const int t    = threadIdx.x;
    const int item = t >> 5;
    const int m    = t & 31;
    const int b    = blockIdx.x * IPB + item;
    const bool active = (m < NCTX);

    float xr[DM], kr[DM], vr[DM];

    if (active) {
        // ---- x row straight to registers (vmcnt only, no LDS stage) ----
        const float4* xp = (const float4*)(x + ((size_t)b * NCTX + m) * DM);
        #pragma unroll
        for (int i = 0; i < 7; ++i) {
            float4 v4 = xp[i];
            xr[4*i+0]=v4.x; xr[4*i+1]=v4.y; xr[4*i+2]=v4.z; xr[4*i+3]=v4.w;
        }

        // ---- q pass (fully unrolled; weights = uniform s_load_dwordx4) ----
        float qr[DM];
        #pragma unroll
        for (int c = 0; c < DM; ++c) qr[c] = bq[c];
        #pragma unroll
        for (int w = 0; w < DM; ++w) {
            const float4* wr = (const float4*)(&g_wt[w*WTS]);
            #pragma unroll
            for (int i = 0; i < 7; ++i) {
                float4 w4 = wr[i];
                qr[4*i+0] = fmaf(xr[w], w4.x, qr[4*i+0]);
                qr[4*i+1] = fmaf(xr[w], w4.y, qr[4*i+1]);
                qr[4*i+2] = fmaf(xr[w], w4.z, qr[4*i+2]);
                qr[4*i+3] = fmaf(xr[w], w4.w, qr[4*i+3]);
            }
        }
        // publish q early; its LDS-write latency hides under the k/v passes
        float4* qdst = (float4*)(&qs[item][m*QSTRIDE]);
        #pragma unroll
        for (int i = 0; i < 7; ++i)
            qdst[i] = make_float4(qr[4*i+0], qr[4*i+1], qr[4*i+2], qr[4*i+3]);

        // ---- k pass ----
        #pragma unroll
        for (int c = 0; c < DM; ++c) kr[c] = bk[c];
        #pragma unroll
        for (int w = 0; w < DM; ++w) {
            const float4* wr = (const float4*)(&g_wt[w*WTS + 28]);
            #pragma unroll
            for (int i = 0; i < 7; ++i) {
                float4 w4 = wr[i];
                kr[4*i+0] = fmaf(xr[w], w4.x, kr[4*i+0]);
                kr[4*i+1] = fmaf(xr[w], w4.y, kr[4*i+1]);
                kr[4*i+2] = fmaf(xr[w], w4.z, kr[4*i+2]);
                kr[4*i+3] = fmaf(xr[w], w4.w, kr[4*i+3]);
            }
        }
        // ---- v pass ----
        #pragma unroll
        for (int c = 0; c < DM; ++c) vr[c] = bv[c];
        #pragma unroll
        for (int w = 0; w < DM; ++w) {
            const float4* wr = (const float4*)(&g_wt[w*WTS + 56]);
            #pragma unroll
            for (int i = 0; i < 7; ++i) {
                float4 w4 = wr[i];
                vr[4*i+0] = fmaf(xr[w], w4.x, vr[4*i+0]);
                vr[4*i+1] = fmaf(xr[w], w4.y, vr[4*i+1]);
                vr[4*i+2] = fmaf(xr[w], w4.z, vr[4*i+2]);
                vr[4*i+3] = fmaf(xr[w], w4.w, vr[4*i+3]);
            }
        }
    }
    __syncthreads();

    if (active) {
        // ---- L1 attention + row-dot with v (k, v register-resident) ----
        const float scale = -0.18898223650461363f;   // -1/sqrt(28)
        const float* qbase = &qs[item][0];
        float acc = 0.f;
        #pragma unroll
        for (int j = 0; j < NCTX; ++j) {
            const float4* qj = (const float4*)(qbase + j*QSTRIDE);  // uniform broadcast
            float s0 = 0.f, s1 = 0.f, s2 = 0.f, s3 = 0.f;
            #pragma unroll
            for (int w4 = 0; w4 < 7; ++w4) {
                float4 qv = qj[w4];
                s0 += fabsf(qv.x - kr[4*w4+0]);
                s1 += fabsf(qv.y - kr[4*w4+1]);
                s2 += fabsf(qv.z - kr[4*w4+2]);
                s3 += fabsf(qv.w - kr[4*w4+3]);
            }
            float a = (j == m) ? 1.0f : scale * ((s0 + s1) + (s2 + s3));
            acc = fmaf(vr[j], a, acc);
        }
        l1_lds[item][m] = acc;
    }
    __syncthreads();

    if (m < 20) {
        float a = b1[m];
        #pragma unroll
        for (int w = 0; w < NCTX; ++w) a += l1_lds[item][w] * W1[m*NCTX + w];
        h_lds[item][m] = fmaxf(a, 0.f);
    }
    __syncthreads();

    if (m < 10) {
        float a = b2[m];
        #pragma unroll
        for (int w = 0; w < 20; ++w) a += h_lds[item][w] * W2[m*20 + w];
        out[(size_t)b*10 + m] = a;
    }
}

extern "C" void kernel_launch(void* const* d_in, const int* in_sizes, int n_in,
                              void* d_out, int out_size, void* d_ws, size_t ws_size,
                              hipStream_t stream) {
    const float* x  = (const float*)d_in[0];
    const float* Wq = (const float*)d_in[1];
    const float* bq = (const float*)d_in[2];
    const float* Wk = (const float*)d_in[3];
    const float* bk = (const float*)d_in[4];
    const float* Wv = (const float*)d_in[5];
    const float* bv = (const float*)d_in[6];
    const float* W1 = (const float*)d_in[7];
    const float* b1 = (const float*)d_in[8];
    const float* W2 = (const float*)d_in[9];
    const float* b2 = (const float*)d_in[10];
    float* out = (float*)d_out;

    hipLaunchKernelGGL(transpose_weights, dim3(1), dim3(256), 0, stream, Wq, Wk, Wv);

    dim3 grid(BS / IPB), block(BLOCK);
    hipLaunchKernelGGL(l1att_fused, grid, block, 0, stream,
                       x, bq, bk, bv, W1, b1, W2, b2, out);
}

// Round 5
// 23.950 us; speedup vs baseline: 3.7541x; 3.7541x over previous
//
#include <hip/hip_runtime.h>
#include <math.h>

#define BS    8192
#define NCTX  28
#define DM    28

typedef __attribute__((ext_vector_type(8))) short  bfx8;
typedef __attribute__((ext_vector_type(16))) float f32x16;

// Load 8 consecutive floats of a row (zero-padding the last 4 when k0==24,
// which also implements the K=28->32 zero pad) and split each into
// bf16-hi (truncate) + bf16-lo (truncate of residual).  err ~2^-16 rel.
__device__ __forceinline__ void load8_cvt(const float* rowbase, int k0,
                                          bfx8& hi, bfx8& lo)
{
    float f[8];
    float4 a = *(const float4*)(rowbase + k0);
    float4 b;
    if (k0 < 24) b = *(const float4*)(rowbase + k0 + 4);
    else         b = make_float4(0.f, 0.f, 0.f, 0.f);
    f[0]=a.x; f[1]=a.y; f[2]=a.z; f[3]=a.w;
    f[4]=b.x; f[5]=b.y; f[6]=b.z; f[7]=b.w;
    #pragma unroll
    for (int j = 0; j < 8; ++j) {
        unsigned xb = __float_as_uint(f[j]);
        unsigned hb = xb & 0xFFFF0000u;
        float    r  = f[j] - __uint_as_float(hb);
        unsigned lb = __float_as_uint(r);
        hi[j] = (short)(hb >> 16);
        lo[j] = (short)(lb >> 16);
    }
}

// One wave = 2 items, whole kernel barrier-free (wave-private LDS regions).
__global__ __launch_bounds__(256, 4) void l1att_mfma(
    const float* __restrict__ x,
    const float* __restrict__ Wq, const float* __restrict__ bq,
    const float* __restrict__ Wk, const float* __restrict__ bk,
    const float* __restrict__ Wv, const float* __restrict__ bv,
    const float* __restrict__ W1, const float* __restrict__ b1,
    const float* __restrict__ W2, const float* __restrict__ b2,
    float* __restrict__ out)
{
    __shared__ float qs [4][2][NCTX*DM];  // persistent q rows, per wave/item
    __shared__ float scr[4][NCTX*DM];     // k/v transpose scratch, per wave
    __shared__ float l1s[4][2][NCTX];
    __shared__ float hs [4][2][20];

    const int tid = threadIdx.x;
    const int wv  = tid >> 6;        // wave in block
    const int l   = tid & 63;        // lane
    const int h   = l >> 5;          // k-group for frags == item-half later
    const int r31 = l & 31;          // row/col within 32-tile == row m later
    const int rc  = (r31 < 28) ? r31 : 0;   // clamped (pad rows/cols -> junk, unread)
    const int ib  = blockIdx.x * 8 + wv * 2;  // first item of this wave

    // ---------- A fragments: x rows, split bf16 ----------
    // mfma_32x32x16 A-layout: lane holds A[row=l&31][k = 16*kt + 8*(l>>5) + j]
    bfx8 Ah[2][2], Al[2][2];
    #pragma unroll
    for (int it = 0; it < 2; ++it)
        #pragma unroll
        for (int kt = 0; kt < 2; ++kt)
            load8_cvt(x + ((size_t)(ib + it) * NCTX + rc) * DM, 16*kt + 8*h,
                      Ah[it][kt], Al[it][kt]);

    float kr[DM], vr[DM];

    // ---------------- q (written to persistent LDS, C-layout -> [m][c]) -------------
    {
        bfx8 Bh[2], Bl[2];   // B[k][n=l&31] = Wq[n][k]
        #pragma unroll
        for (int kt = 0; kt < 2; ++kt)
            load8_cvt(Wq + rc*DM, 16*kt + 8*h, Bh[kt], Bl[kt]);
        float bc = bq[rc];
        #pragma unroll
        for (int it = 0; it < 2; ++it) {
            f32x16 acc;
            #pragma unroll
            for (int r = 0; r < 16; ++r) acc[r] = bc;   // bias via C-init (col=lane)
            acc = __builtin_amdgcn_mfma_f32_32x32x16_bf16(Ah[it][0], Bh[0], acc, 0,0,0);
            acc = __builtin_amdgcn_mfma_f32_32x32x16_bf16(Ah[it][1], Bh[1], acc, 0,0,0);
            acc = __builtin_amdgcn_mfma_f32_32x32x16_bf16(Ah[it][0], Bl[0], acc, 0,0,0);
            acc = __builtin_amdgcn_mfma_f32_32x32x16_bf16(Ah[it][1], Bl[1], acc, 0,0,0);
            acc = __builtin_amdgcn_mfma_f32_32x32x16_bf16(Al[it][0], Bh[0], acc, 0,0,0);
            acc = __builtin_amdgcn_mfma_f32_32x32x16_bf16(Al[it][1], Bh[1], acc, 0,0,0);
            if (r31 < 28) {
                #pragma unroll
                for (int r = 0; r < 16; ++r) {
                    int row = (r & 3) + 8*(r >> 2) + 4*h;
                    if (row < 28) qs[wv][it][row*DM + r31] = acc[r];
                }
            }
        }
    }

    // ---------------- k (scratch round-trip -> kr registers) ----------------
    {
        bfx8 Bh[2], Bl[2];
        #pragma unroll
        for (int kt = 0; kt < 2; ++kt)
            load8_cvt(Wk + rc*DM, 16*kt + 8*h, Bh[kt], Bl[kt]);
        float bc = bk[rc];
        #pragma unroll
        for (int it = 0; it < 2; ++it) {
            f32x16 acc;
            #pragma unroll
            for (int r = 0; r < 16; ++r) acc[r] = bc;
            acc = __builtin_amdgcn_mfma_f32_32x32x16_bf16(Ah[it][0], Bh[0], acc, 0,0,0);
            acc = __builtin_amdgcn_mfma_f32_32x32x16_bf16(Ah[it][1], Bh[1], acc, 0,0,0);
            acc = __builtin_amdgcn_mfma_f32_32x32x16_bf16(Ah[it][0], Bl[0], acc, 0,0,0);
            acc = __builtin_amdgcn_mfma_f32_32x32x16_bf16(Ah[it][1], Bl[1], acc, 0,0,0);
            acc = __builtin_amdgcn_mfma_f32_32x32x16_bf16(Al[it][0], Bh[0], acc, 0,0,0);
            acc = __builtin_amdgcn_mfma_f32_32x32x16_bf16(Al[it][1], Bh[1], acc, 0,0,0);
            if (r31 < 28) {
                #pragma unroll
                for (int r = 0; r < 16; ++r) {
                    int row = (r & 3) + 8*(r >> 2) + 4*h;
                    if (row < 28) scr[wv][row*DM + r31] = acc[r];
                }
            }
            // lanes of half `it` read their row back before next it overwrites
            if (h == it && r31 < 28) {
                const float4* kp = (const float4*)&scr[wv][r31*DM];
                #pragma unroll
                for (int i = 0; i < 7; ++i) {
                    float4 t = kp[i];
                    kr[4*i+0]=t.x; kr[4*i+1]=t.y; kr[4*i+2]=t.z; kr[4*i+3]=t.w;
                }
            }
        }
    }

    // ---------------- v (same pattern -> vr registers) ----------------
    {
        bfx8 Bh[2], Bl[2];
        #pragma unroll
        for (int kt = 0; kt < 2; ++kt)
            load8_cvt(Wv + rc*DM, 16*kt + 8*h, Bh[kt], Bl[kt]);
        float bc = bv[rc];
        #pragma unroll
        for (int it = 0; it < 2; ++it) {
            f32x16 acc;
            #pragma unroll
            for (int r = 0; r < 16; ++r) acc[r] = bc;
            acc = __builtin_amdgcn_mfma_f32_32x32x16_bf16(Ah[it][0], Bh[0], acc, 0,0,0);
            acc = __builtin_amdgcn_mfma_f32_32x32x16_bf16(Ah[it][1], Bh[1], acc, 0,0,0);
            acc = __builtin_amdgcn_mfma_f32_32x32x16_bf16(Ah[it][0], Bl[0], acc, 0,0,0);
            acc = __builtin_amdgcn_mfma_f32_32x32x16_bf16(Ah[it][1], Bl[1], acc, 0,0,0);
            acc = __builtin_amdgcn_mfma_f32_32x32x16_bf16(Al[it][0], Bh[0], acc, 0,0,0);
            acc = __builtin_amdgcn_mfma_f32_32x32x16_bf16(Al[it][1], Bh[1], acc, 0,0,0);
            if (r31 < 28) {
                #pragma unroll
                for (int r = 0; r < 16; ++r) {
                    int row = (r & 3) + 8*(r >> 2) + 4*h;
                    if (row < 28) scr[wv][row*DM + r31] = acc[r];
                }
            }
            if (h == it && r31 < 28) {
                const float4* vp = (const float4*)&scr[wv][r31*DM];
                #pragma unroll
                for (int i = 0; i < 7; ++i) {
                    float4 t = vp[i];
                    vr[4*i+0]=t.x; vr[4*i+1]=t.y; vr[4*i+2]=t.z; vr[4*i+3]=t.w;
                }
            }
        }
    }

    // ---------------- L1 attention + row-dot with v ----------------
    if (r31 < 28) {
        const float scale = -0.18898223650461363f;   // -1/sqrt(28)
        const float* qb = &qs[wv][h][0];
        float acc = 0.f;
        #pragma unroll
        for (int j = 0; j < NCTX; ++j) {
            const float4* qj = (const float4*)(qb + j*DM);  // half-uniform broadcast
            float s0=0.f, s1=0.f, s2=0.f, s3=0.f;
            #pragma unroll
            for (int w4 = 0; w4 < 7; ++w4) {
                float4 qv = qj[w4];
                s0 += fabsf(qv.x - kr[4*w4+0]);
                s1 += fabsf(qv.y - kr[4*w4+1]);
                s2 += fabsf(qv.z - kr[4*w4+2]);
                s3 += fabsf(qv.w - kr[4*w4+3]);
            }
            float a = (j == r31) ? 1.0f : scale * ((s0 + s1) + (s2 + s3));
            acc = fmaf(vr[j], a, acc);
        }
        l1s[wv][h][r31] = acc;
    }

    // ---------------- MLP (same-wave LDS deps, no barrier) ----------------
    if (r31 < 20) {
        float a = b1[r31];
        #pragma unroll
        for (int w = 0; w < NCTX; ++w) a += l1s[wv][h][w] * W1[r31*NCTX + w];
        hs[wv][h][r31] = fmaxf(a, 0.f);
    }
    if (r31 < 10) {
        float a = b2[r31];
        #pragma unroll
        for (int w = 0; w < 20; ++w) a += hs[wv][h][w] * W2[r31*20 + w];
        out[(size_t)(ib + h)*10 + r31] = a;
    }
}

extern "C" void kernel_launch(void* const* d_in, const int* in_sizes, int n_in,
                              void* d_out, int out_size, void* d_ws, size_t ws_size,
                              hipStream_t stream) {
    const float* x  = (const float*)d_in[0];
    const float* Wq = (const float*)d_in[1];
    const float* bq = (const float*)d_in[2];
    const float* Wk = (const float*)d_in[3];
    const float* bk = (const float*)d_in[4];
    const float* Wv = (const float*)d_in[5];
    const float* bv = (const float*)d_in[6];
    const float* W1 = (const float*)d_in[7];
    const float* b1 = (const float*)d_in[8];
    const float* W2 = (const float*)d_in[9];
    const float* b2 = (const float*)d_in[10];
    float* out = (float*)d_out;

    dim3 grid(BS / 8), block(256);
    hipLaunchKernelGGL(l1att_mfma, grid, block, 0, stream,
                       x, Wq, bq, Wk, bk, Wv, bv, W1, b1, W2, b2, out);
}